// Round 1
// baseline (1289.286 us; speedup 1.0000x reference)
//
#include <hip/hip_runtime.h>
#include <stdint.h>

#define NN 50000
#define CC 1024
#define HH 128
#define EE 1600000
#define EPSV 1e-8f

typedef __attribute__((ext_vector_type(8))) short bf16x8;
typedef __attribute__((ext_vector_type(4))) float f32x4;
typedef __attribute__((ext_vector_type(16))) float f32x16;
typedef __attribute__((ext_vector_type(2))) float f32x2;

__device__ __forceinline__ unsigned short f32_to_bf16(float f){
  union { float f; uint32_t u; } cv; cv.f = f;
  uint32_t u = cv.u;
  return (unsigned short)((u + 0x7FFFu + ((u >> 16) & 1u)) >> 16);
}

// ---------------- prep kernels (tiny, once per call) ----------------

__global__ __launch_bounds__(256) void k_prep_w1t(const float* __restrict__ W1,
                                                  unsigned short* __restrict__ W1T){
  int idx = blockIdx.x*256 + threadIdx.x;          // 128*1024 outputs, W1T[n][k]
  if(idx >= 128*1024) return;
  int n = idx >> 10, k = idx & 1023;
  W1T[idx] = f32_to_bf16(W1[k*128 + n]);
}

__global__ __launch_bounds__(256) void k_prep_w2t(const float* __restrict__ W2,
                                                  unsigned short* __restrict__ W2T){
  int idx = blockIdx.x*256 + threadIdx.x;          // 128*128, W2T[n][k]
  if(idx >= 128*128) return;
  int n = idx >> 7, k = idx & 127;
  W2T[idx] = f32_to_bf16(W2[k*128 + n]);
}

// Wg1 pre-fragmented for mfma_f32_32x32x16_bf16 B operand:
// F[ks][nt][lane][j] = Wg1[ks*16 + 8*(lane>>5) + j][nt*32 + (lane&31)]
__global__ __launch_bounds__(256) void k_prep_wg1(const float* __restrict__ Wg1,
                                                  unsigned short* __restrict__ F){
  int idx = blockIdx.x*256 + threadIdx.x;          // 16*4*64*8 = 32768
  if(idx >= 32768) return;
  int j = idx & 7, lane = (idx>>3) & 63, nt = (idx>>9) & 3, ks = idx >> 11;
  int k = ks*16 + ((lane>>5)<<3) + j;
  int n = nt*32 + (lane & 31);
  F[idx] = f32_to_bf16(Wg1[k*128 + n]);
}

// c[e] = base_w[e] * sigmoid(rho_raw[src]) * sigmoid(rho_raw[dst])
__global__ __launch_bounds__(256) void k_edge_c(const int* __restrict__ src,
    const int* __restrict__ dst, const float* __restrict__ base_w,
    const float* __restrict__ rho_raw, float* __restrict__ c){
  int e = blockIdx.x*256 + threadIdx.x;
  if(e >= EE) return;
  float rs = 1.f/(1.f + __expf(-rho_raw[src[e]]));
  float rd = 1.f/(1.f + __expf(-rho_raw[dst[e]]));
  c[e] = base_w[e]*rs*rd;
}

// ---------------- CSR build (histogram + scan + fill) ----------------

__global__ __launch_bounds__(256) void k_hist(const int* __restrict__ dst,
                                              int* __restrict__ counts){
  int e = blockIdx.x*256 + threadIdx.x;
  if(e < EE) atomicAdd(&counts[dst[e]], 1);
}

__global__ __launch_bounds__(1024) void k_scan(const int* __restrict__ counts,
    int* __restrict__ row_ptr, int* __restrict__ cursor){
  __shared__ int buf[1024];
  __shared__ int carry_s;
  const int t = threadIdx.x;
  if(t == 0) carry_s = 0;
  __syncthreads();
  for(int base = 0; base < NN; base += 1024){
    int v = (base+t < NN) ? counts[base+t] : 0;
    buf[t] = v;
    __syncthreads();
    for(int off = 1; off < 1024; off <<= 1){   // Hillis-Steele inclusive scan
      int add = (t >= off) ? buf[t-off] : 0;
      __syncthreads();
      buf[t] += add;
      __syncthreads();
    }
    int carry = carry_s;
    if(base+t < NN){
      int excl = carry + buf[t] - v;
      row_ptr[base+t] = excl;
      cursor[base+t]  = excl;
    }
    __syncthreads();
    if(t == 1023) carry_s = carry + buf[1023];
    __syncthreads();
  }
  if(t == 0) row_ptr[NN] = carry_s;
}

__global__ __launch_bounds__(256) void k_fill(const int* __restrict__ src,
    const int* __restrict__ dst, int* __restrict__ cursor,
    int* __restrict__ csr_pos, int* __restrict__ src_perm){
  int e = blockIdx.x*256 + threadIdx.x;
  if(e >= EE) return;
  int p = atomicAdd(&cursor[dst[e]], 1);
  csr_pos[e] = p;
  src_perm[p] = src[e];
}

// ---------------- encoder: h = relu(relu(X@W1+b1)@W2+b2), bf16 MFMA ----------------
// block = 256 threads (4 waves), tile = 64 rows x 128 cols, K-step 32.

__global__ __launch_bounds__(256) void k_encoder(
    const float* __restrict__ X, const unsigned short* __restrict__ W1T,
    const float* __restrict__ b1, const unsigned short* __restrict__ W2T,
    const float* __restrict__ b2, float* __restrict__ h_f32,
    unsigned short* __restrict__ h_bf16)
{
  __shared__ __attribute__((aligned(16))) unsigned short xA[64][40];    // +8 pad
  __shared__ __attribute__((aligned(16))) unsigned short wB[128][40];
  __shared__ __attribute__((aligned(16))) unsigned short h1s[64][136];  // +8 pad
  __shared__ __attribute__((aligned(16))) unsigned short w2s[128][136];

  const int t = threadIdx.x;
  const int wave = t >> 6, lane = t & 63;
  const int rowL = lane & 15, kq = lane >> 4;
  const int row0 = blockIdx.x * 64;

  // stage full W2T [128][128]
  for(int i = t; i < 2048; i += 256){
    int n = i >> 4, k8 = (i & 15) * 8;
    *(bf16x8*)&w2s[n][k8] = *(const bf16x8*)&W2T[n*128 + k8];
  }

  f32x4 acc[8] = {};
  for(int k0 = 0; k0 < 1024; k0 += 32){
    { // stage X tile 64x32 f32->bf16
      int r = t >> 2, cbase = (t & 3) * 8;
      int gr = row0 + r; if(gr >= NN) gr = NN-1;
      const float* px = X + (size_t)gr*1024 + k0 + cbase;
      f32x4 v0 = *(const f32x4*)px;
      f32x4 v1 = *(const f32x4*)(px + 4);
      union { bf16x8 v; unsigned short s[8]; } pk;
      #pragma unroll
      for(int j = 0; j < 4; j++){ pk.s[j] = f32_to_bf16(v0[j]); pk.s[4+j] = f32_to_bf16(v1[j]); }
      *(bf16x8*)&xA[r][cbase] = pk.v;
    }
    { // stage W1T tile 128x32
      int n = t >> 1, cb = (t & 1) * 16;
      const unsigned short* p = W1T + n*1024 + k0 + cb;
      *(bf16x8*)&wB[n][cb]     = *(const bf16x8*)p;
      *(bf16x8*)&wB[n][cb + 8] = *(const bf16x8*)(p + 8);
    }
    __syncthreads();
    // A frag: lane L -> X[L%16][8*(L/16)+j]; B frag: lane L -> W1T[n0+L%16][8*(L/16)+j]
    bf16x8 a = *(const bf16x8*)&xA[wave*16 + rowL][kq*8];
    #pragma unroll
    for(int nt = 0; nt < 8; nt++){
      bf16x8 b = *(const bf16x8*)&wB[nt*16 + rowL][kq*8];
      acc[nt] = __builtin_amdgcn_mfma_f32_16x16x32_bf16(a, b, acc[nt], 0, 0, 0);
    }
    __syncthreads();
  }

  // h1 = relu(acc + b1) -> LDS bf16.  D: row = 4*(L>>4)+r, col = nt*16 + (L&15)
  #pragma unroll
  for(int nt = 0; nt < 8; nt++){
    #pragma unroll
    for(int r = 0; r < 4; r++){
      int rr_ = wave*16 + kq*4 + r;
      int cc  = nt*16 + rowL;
      h1s[rr_][cc] = f32_to_bf16(fmaxf(acc[nt][r] + b1[cc], 0.f));
    }
  }
  __syncthreads();

  f32x4 acc2[8] = {};
  #pragma unroll
  for(int ks = 0; ks < 4; ks++){
    bf16x8 a = *(const bf16x8*)&h1s[wave*16 + rowL][ks*32 + kq*8];
    #pragma unroll
    for(int nt = 0; nt < 8; nt++){
      bf16x8 b = *(const bf16x8*)&w2s[nt*16 + rowL][ks*32 + kq*8];
      acc2[nt] = __builtin_amdgcn_mfma_f32_16x16x32_bf16(a, b, acc2[nt], 0, 0, 0);
    }
  }
  #pragma unroll
  for(int nt = 0; nt < 8; nt++){
    #pragma unroll
    for(int r = 0; r < 4; r++){
      int gr = row0 + wave*16 + kq*4 + r;
      if(gr < NN){
        int cc = nt*16 + rowL;
        float v = fmaxf(acc2[nt][r] + b2[cc], 0.f);
        h_f32[(size_t)gr*128 + cc]  = v;
        h_bf16[(size_t)gr*128 + cc] = f32_to_bf16(v);
      }
    }
  }
}

// ---------------- edge gate: w_perm[csr_pos[e]] = c[e]*sigmoid(MLP(z)) ----------------
// block = 256 (4 waves), 64 edges/wave, mfma_f32_32x32x16_bf16.
// A = z rows (gathered 16B loads from bf16 h table), B = pre-fragmented Wg1 in LDS.

__global__ __launch_bounds__(256) void k_gate(
    const unsigned short* __restrict__ h,
    const int* __restrict__ src, const int* __restrict__ dst,
    const float* __restrict__ c, const int* __restrict__ csr_pos,
    const unsigned short* __restrict__ Wg1f,
    const float* __restrict__ bg1, const float* __restrict__ Wg2,
    const float* __restrict__ bg2p, float* __restrict__ w_perm)
{
  __shared__ __attribute__((aligned(16))) unsigned short Bf[32768];  // 64 KB
  const int t = threadIdx.x, wave = t >> 6, lane = t & 63;
  const int l31 = lane & 31, hi = lane >> 5;

  for(int i = t; i < 4096; i += 256)
    *(bf16x8*)&Bf[i*8] = *(const bf16x8*)&Wg1f[i*8];

  const int e0  = blockIdx.x*256 + wave*64;
  const int eA0 = e0 + l31, eA1 = e0 + 32 + l31;   // edge owned per A-lane (M-tile 0/1)
  const unsigned short* rS0 = h + (size_t)src[eA0]*128;
  const unsigned short* rD0 = h + (size_t)dst[eA0]*128;
  const unsigned short* rS1 = h + (size_t)src[eA1]*128;
  const unsigned short* rD1 = h + (size_t)dst[eA1]*128;

  f32x16 acc[2][4] = {};
  __syncthreads();

  // z = [h_src | h_dst]; k = ks*16 + 8*hi + j. ks<8 -> src half, ks>=8 -> dst half.
  #pragma unroll
  for(int ks = 0; ks < 16; ks++){
    const unsigned short* r0 = (ks < 8) ? rS0 : rD0;
    const unsigned short* r1 = (ks < 8) ? rS1 : rD1;
    const int koff = (ks & 7)*16 + hi*8;
    bf16x8 a0 = *(const bf16x8*)&r0[koff];
    bf16x8 a1 = *(const bf16x8*)&r1[koff];
    #pragma unroll
    for(int nt = 0; nt < 4; nt++){
      bf16x8 b = *(const bf16x8*)&Bf[(ks*4 + nt)*512 + lane*8];
      acc[0][nt] = __builtin_amdgcn_mfma_f32_32x32x16_bf16(a0, b, acc[0][nt], 0, 0, 0);
      acc[1][nt] = __builtin_amdgcn_mfma_f32_32x32x16_bf16(a1, b, acc[1][nt], 0, 0, 0);
    }
  }

  // finish MLP: relu(+bg1) dot Wg2, reduce over the 32 lanes of each half.
  float bg1v[4], wg2v[4];
  #pragma unroll
  for(int nt = 0; nt < 4; nt++){ int cc = nt*32 + l31; bg1v[nt] = bg1[cc]; wg2v[nt] = Wg2[cc]; }
  const float bg2v = bg2p[0];

  float part[2][16];
  #pragma unroll
  for(int mt = 0; mt < 2; mt++)
    #pragma unroll
    for(int r = 0; r < 16; r++){
      float s = 0.f;
      #pragma unroll
      for(int nt = 0; nt < 4; nt++)
        s += fmaxf(acc[mt][nt][r] + bg1v[nt], 0.f) * wg2v[nt];
      part[mt][r] = s;
    }
  #pragma unroll
  for(int off = 1; off < 32; off <<= 1){
    #pragma unroll
    for(int mt = 0; mt < 2; mt++)
      #pragma unroll
      for(int r = 0; r < 16; r++)
        part[mt][r] += __shfl_xor(part[mt][r], off);
  }

  // D row = (r&3) + 8*(r>>2) + 4*hi; one lane per (mt,r) writes its edge.
  #pragma unroll
  for(int mt = 0; mt < 2; mt++){
    #pragma unroll
    for(int r = 0; r < 16; r++){
      if(l31 == mt*16 + r){
        float logit = part[mt][r] + bg2v;
        float g = 1.f/(1.f + __expf(-logit));
        int m = (r & 3) + 8*(r >> 2) + 4*hi;
        int e = e0 + mt*32 + m;
        w_perm[csr_pos[e]] = c[e]*g;
      }
    }
  }
}

// ---------------- aggregation: h_out[n] = sum(w*h_src)/(sum(w)+eps), CSR gather ----------------
// one wave per node, 2 f32 per lane.

__global__ __launch_bounds__(256) void k_aggregate(
    const float* __restrict__ hsrc,
    const int* __restrict__ row_ptr, const int* __restrict__ src_perm,
    const float* __restrict__ w_perm,
    float* __restrict__ out_f32, unsigned short* __restrict__ out_bf16)
{
  const int gw = (blockIdx.x*256 + threadIdx.x) >> 6;
  const int lane = threadIdx.x & 63;
  if(gw >= NN) return;
  const int beg = row_ptr[gw], end = row_ptr[gw+1];
  float a0 = 0.f, a1 = 0.f, wsum = 0.f;
  for(int i = beg; i < end; i++){
    const float w = w_perm[i];
    const int s = src_perm[i];
    const f32x2 rv = *(const f32x2*)&hsrc[(size_t)s*128 + lane*2];
    a0 += w*rv[0]; a1 += w*rv[1]; wsum += w;
  }
  const float inv = 1.f/(wsum + EPSV);
  const float v0 = a0*inv, v1 = a1*inv;
  const size_t o = (size_t)gw*128 + lane*2;
  *(f32x2*)&out_f32[o] = (f32x2){v0, v1};
  if(out_bf16){ out_bf16[o] = f32_to_bf16(v0); out_bf16[o+1] = f32_to_bf16(v1); }
}

// ---------------- launch ----------------

extern "C" void kernel_launch(void* const* d_in, const int* in_sizes, int n_in,
                              void* d_out, int out_size, void* d_ws, size_t ws_size,
                              hipStream_t stream) {
  (void)in_sizes; (void)n_in; (void)out_size; (void)ws_size;
  const float* X      = (const float*)d_in[0];
  const int*   src    = (const int*)d_in[1];
  const int*   dst    = (const int*)d_in[2];
  const float* base_w = (const float*)d_in[3];
  const float* W1     = (const float*)d_in[4];
  const float* b1     = (const float*)d_in[5];
  const float* W2     = (const float*)d_in[6];
  const float* b2     = (const float*)d_in[7];
  const float* Wg1    = (const float*)d_in[8];
  const float* bg1    = (const float*)d_in[9];
  const float* Wg2    = (const float*)d_in[10];
  const float* bg2    = (const float*)d_in[11];
  const float* rho    = (const float*)d_in[12];

  char* ws = (char*)d_ws;
  size_t off = 0;
  auto alloc = [&](size_t bytes)->char*{ char* p = ws + off; off += (bytes + 255) & ~(size_t)255; return p; };
  unsigned short* W1T      = (unsigned short*)alloc((size_t)1024*128*2);
  unsigned short* W2T      = (unsigned short*)alloc((size_t)128*128*2);
  unsigned short* Wg1f     = (unsigned short*)alloc((size_t)32768*2);
  float*          cbuf     = (float*)alloc((size_t)EE*4);
  int*            csr_pos  = (int*)alloc((size_t)EE*4);
  int*            src_perm = (int*)alloc((size_t)EE*4);
  float*          w_perm   = (float*)alloc((size_t)EE*4);
  int*            row_ptr  = (int*)alloc((size_t)(NN+1)*4);
  int*            cursor   = (int*)alloc((size_t)NN*4);
  int*            counts   = (int*)alloc((size_t)NN*4);
  unsigned short* hb_A     = (unsigned short*)alloc((size_t)NN*128*2);
  unsigned short* hb_B     = (unsigned short*)alloc((size_t)NN*128*2);
  float*          hf_B     = (float*)alloc((size_t)NN*128*4);
  float*          h0       = (float*)d_out;   // encoder output lives in d_out (read by layer-1 agg)

  hipMemsetAsync(counts, 0, (size_t)NN*4, stream);
  k_prep_w1t<<<512, 256, 0, stream>>>(W1, W1T);
  k_prep_w2t<<<64, 256, 0, stream>>>(W2, W2T);
  k_prep_wg1<<<128, 256, 0, stream>>>(Wg1, Wg1f);
  k_edge_c<<<EE/256, 256, 0, stream>>>(src, dst, base_w, rho, cbuf);
  k_hist<<<EE/256, 256, 0, stream>>>(dst, counts);
  k_scan<<<1, 1024, 0, stream>>>(counts, row_ptr, cursor);
  k_fill<<<EE/256, 256, 0, stream>>>(src, dst, cursor, csr_pos, src_perm);

  k_encoder<<<782, 256, 0, stream>>>(X, W1T, b1, W2T, b2, h0, hb_A);

  // layer 1
  k_gate<<<EE/256, 256, 0, stream>>>(hb_A, src, dst, cbuf, csr_pos, Wg1f, bg1, Wg2, bg2, w_perm);
  k_aggregate<<<NN/4, 256, 0, stream>>>(h0, row_ptr, src_perm, w_perm, hf_B, hb_B);
  // layer 2
  k_gate<<<EE/256, 256, 0, stream>>>(hb_B, src, dst, cbuf, csr_pos, Wg1f, bg1, Wg2, bg2, w_perm);
  k_aggregate<<<NN/4, 256, 0, stream>>>(hf_B, row_ptr, src_perm, w_perm, (float*)d_out, nullptr);
}

// Round 2
// 815.303 us; speedup vs baseline: 1.5814x; 1.5814x over previous
//
#include <hip/hip_runtime.h>
#include <stdint.h>

#define NN 50000
#define CC 1024
#define HH 128
#define EE 1600000
#define EPSV 1e-8f

typedef __attribute__((ext_vector_type(8))) short bf16x8;
typedef __attribute__((ext_vector_type(4))) float f32x4;
typedef __attribute__((ext_vector_type(2))) float f32x2;

__device__ __forceinline__ unsigned short f32_to_bf16(float f){
  union { float f; uint32_t u; } cv; cv.f = f;
  uint32_t u = cv.u;
  return (unsigned short)((u + 0x7FFFu + ((u >> 16) & 1u)) >> 16);
}
__device__ __forceinline__ float bf16_to_f32(unsigned short s){
  union { uint32_t u; float f; } cv; cv.u = ((uint32_t)s) << 16; return cv.f;
}

// ---------------- prep kernels ----------------

__global__ __launch_bounds__(256) void k_prep_w1t(const float* __restrict__ W1,
                                                  unsigned short* __restrict__ W1T){
  int idx = blockIdx.x*256 + threadIdx.x;          // 128*1024, W1T[n][k]
  if(idx >= 128*1024) return;
  int n = idx >> 10, k = idx & 1023;
  W1T[idx] = f32_to_bf16(W1[k*128 + n]);
}

__global__ __launch_bounds__(256) void k_prep_w2t(const float* __restrict__ W2,
                                                  unsigned short* __restrict__ W2T){
  int idx = blockIdx.x*256 + threadIdx.x;          // 128*128, W2T[n][k]
  if(idx >= 128*128) return;
  int n = idx >> 7, k = idx & 127;
  W2T[idx] = f32_to_bf16(W2[k*128 + n]);
}

// Wg1T[c][k], c in [0,256): c<128 -> u-col c uses Wg1[k][c]; c>=128 -> v-col uses Wg1[128+k][c-128]
__global__ __launch_bounds__(256) void k_prep_wg1T(const float* __restrict__ Wg1,
                                                   unsigned short* __restrict__ T){
  int idx = blockIdx.x*256 + threadIdx.x;          // 256*128
  if(idx >= 256*128) return;
  int c = idx >> 7, k = idx & 127;
  int row = (c < 128) ? k : (128 + k);
  int col = (c < 128) ? c : (c - 128);
  T[idx] = f32_to_bf16(Wg1[row*128 + col]);
}

// ---------------- CSR build ----------------

__global__ __launch_bounds__(256) void k_hist(const int* __restrict__ dst,
                                              int* __restrict__ counts){
  int e = blockIdx.x*256 + threadIdx.x;
  if(e < EE) atomicAdd(&counts[dst[e]], 1);
}

__global__ __launch_bounds__(1024) void k_scan(const int* __restrict__ counts,
    int* __restrict__ row_ptr, int* __restrict__ cursor){
  __shared__ int buf[1024];
  __shared__ int carry_s;
  const int t = threadIdx.x;
  if(t == 0) carry_s = 0;
  __syncthreads();
  for(int base = 0; base < NN; base += 1024){
    int v = (base+t < NN) ? counts[base+t] : 0;
    buf[t] = v;
    __syncthreads();
    for(int off = 1; off < 1024; off <<= 1){
      int add = (t >= off) ? buf[t-off] : 0;
      __syncthreads();
      buf[t] += add;
      __syncthreads();
    }
    int carry = carry_s;
    if(base+t < NN){
      int excl = carry + buf[t] - v;
      row_ptr[base+t] = excl;
      cursor[base+t]  = excl;
    }
    __syncthreads();
    if(t == 1023) carry_s = carry + buf[1023];
    __syncthreads();
  }
  if(t == 0) row_ptr[NN] = carry_s;
}

// fill CSR slots; computes c = base_w*sig(rho_src)*sig(rho_dst) inline into permuted order
__global__ __launch_bounds__(256) void k_fill(const int* __restrict__ src,
    const int* __restrict__ dst, const float* __restrict__ base_w,
    const float* __restrict__ rho_raw, int* __restrict__ cursor,
    int* __restrict__ src_perm, float* __restrict__ c_perm){
  int e = blockIdx.x*256 + threadIdx.x;
  if(e >= EE) return;
  int s = src[e], d = dst[e];
  int p = atomicAdd(&cursor[d], 1);
  float rs = 1.f/(1.f + __expf(-rho_raw[s]));
  float rd = 1.f/(1.f + __expf(-rho_raw[d]));
  src_perm[p] = s;
  c_perm[p]   = base_w[e]*rs*rd;
}

// ---------------- encoder: h = relu(relu(X@W1+b1)@W2+b2) -> f32 ----------------

__global__ __launch_bounds__(256) void k_encoder(
    const float* __restrict__ X, const unsigned short* __restrict__ W1T,
    const float* __restrict__ b1, const unsigned short* __restrict__ W2T,
    const float* __restrict__ b2, float* __restrict__ h_f32)
{
  __shared__ __attribute__((aligned(16))) unsigned short xA[64][40];
  __shared__ __attribute__((aligned(16))) unsigned short wB[128][40];
  __shared__ __attribute__((aligned(16))) unsigned short h1s[64][136];
  __shared__ __attribute__((aligned(16))) unsigned short w2s[128][136];

  const int t = threadIdx.x;
  const int wave = t >> 6, lane = t & 63;
  const int rowL = lane & 15, kq = lane >> 4;
  const int row0 = blockIdx.x * 64;

  for(int i = t; i < 2048; i += 256){
    int n = i >> 4, k8 = (i & 15) * 8;
    *(bf16x8*)&w2s[n][k8] = *(const bf16x8*)&W2T[n*128 + k8];
  }

  f32x4 acc[8] = {};
  for(int k0 = 0; k0 < 1024; k0 += 32){
    {
      int r = t >> 2, cbase = (t & 3) * 8;
      int gr = row0 + r; if(gr >= NN) gr = NN-1;
      const float* px = X + (size_t)gr*1024 + k0 + cbase;
      f32x4 v0 = *(const f32x4*)px;
      f32x4 v1 = *(const f32x4*)(px + 4);
      union { bf16x8 v; unsigned short s[8]; } pk;
      #pragma unroll
      for(int j = 0; j < 4; j++){ pk.s[j] = f32_to_bf16(v0[j]); pk.s[4+j] = f32_to_bf16(v1[j]); }
      *(bf16x8*)&xA[r][cbase] = pk.v;
    }
    {
      int n = t >> 1, cb = (t & 1) * 16;
      const unsigned short* p = W1T + n*1024 + k0 + cb;
      *(bf16x8*)&wB[n][cb]     = *(const bf16x8*)p;
      *(bf16x8*)&wB[n][cb + 8] = *(const bf16x8*)(p + 8);
    }
    __syncthreads();
    bf16x8 a = *(const bf16x8*)&xA[wave*16 + rowL][kq*8];
    #pragma unroll
    for(int nt = 0; nt < 8; nt++){
      bf16x8 b = *(const bf16x8*)&wB[nt*16 + rowL][kq*8];
      acc[nt] = __builtin_amdgcn_mfma_f32_16x16x32_bf16(a, b, acc[nt], 0, 0, 0);
    }
    __syncthreads();
  }

  #pragma unroll
  for(int nt = 0; nt < 8; nt++){
    #pragma unroll
    for(int r = 0; r < 4; r++){
      int rr_ = wave*16 + kq*4 + r;
      int cc  = nt*16 + rowL;
      h1s[rr_][cc] = f32_to_bf16(fmaxf(acc[nt][r] + b1[cc], 0.f));
    }
  }
  __syncthreads();

  f32x4 acc2[8] = {};
  #pragma unroll
  for(int ks = 0; ks < 4; ks++){
    bf16x8 a = *(const bf16x8*)&h1s[wave*16 + rowL][ks*32 + kq*8];
    #pragma unroll
    for(int nt = 0; nt < 8; nt++){
      bf16x8 b = *(const bf16x8*)&w2s[nt*16 + rowL][ks*32 + kq*8];
      acc2[nt] = __builtin_amdgcn_mfma_f32_16x16x32_bf16(a, b, acc2[nt], 0, 0, 0);
    }
  }
  #pragma unroll
  for(int nt = 0; nt < 8; nt++){
    #pragma unroll
    for(int r = 0; r < 4; r++){
      int gr = row0 + wave*16 + kq*4 + r;
      if(gr < NN){
        int cc = nt*16 + rowL;
        h_f32[(size_t)gr*128 + cc] = fmaxf(acc2[nt][r] + b2[cc], 0.f);
      }
    }
  }
}

// ---------------- UV = h @ Wg1T' : [N,128] -> [N,256] bf16 (u | v) ----------------
// block 256 (4 waves), tile 64 rows x 256 cols; B-frags read from global (L1/L2-resident 64KB)

__global__ __launch_bounds__(256) void k_uv(
    const float* __restrict__ hf, const unsigned short* __restrict__ Wg1T,
    unsigned short* __restrict__ UV)
{
  __shared__ __attribute__((aligned(16))) unsigned short As[64][136];
  const int t = threadIdx.x, wave = t >> 6, lane = t & 63;
  const int rowL = lane & 15, kq = lane >> 4;
  const int row0 = blockIdx.x * 64;

  {
    int r = t >> 2, cb = (t & 3) * 32;
    int gr = row0 + r; if(gr >= NN) gr = NN-1;
    const float* p = hf + (size_t)gr*128 + cb;
    #pragma unroll
    for(int j8 = 0; j8 < 4; j8++){
      f32x4 v0 = *(const f32x4*)(p + j8*8);
      f32x4 v1 = *(const f32x4*)(p + j8*8 + 4);
      union { bf16x8 v; unsigned short s[8]; } pk;
      #pragma unroll
      for(int j = 0; j < 4; j++){ pk.s[j] = f32_to_bf16(v0[j]); pk.s[4+j] = f32_to_bf16(v1[j]); }
      *(bf16x8*)&As[r][cb + j8*8] = pk.v;
    }
  }
  __syncthreads();

  f32x4 acc[16] = {};
  #pragma unroll
  for(int ks = 0; ks < 4; ks++){
    bf16x8 a = *(const bf16x8*)&As[wave*16 + rowL][ks*32 + kq*8];
    #pragma unroll
    for(int nt = 0; nt < 16; nt++){
      bf16x8 b = *(const bf16x8*)&Wg1T[(size_t)(nt*16 + rowL)*128 + ks*32 + kq*8];
      acc[nt] = __builtin_amdgcn_mfma_f32_16x16x32_bf16(a, b, acc[nt], 0, 0, 0);
    }
  }
  #pragma unroll
  for(int nt = 0; nt < 16; nt++){
    #pragma unroll
    for(int r = 0; r < 4; r++){
      int gr = row0 + wave*16 + kq*4 + r;
      if(gr < NN) UV[(size_t)gr*256 + nt*16 + rowL] = f32_to_bf16(acc[nt][r]);
    }
  }
}

// ---------------- fused gate + aggregation, CSR order, one wave per dst node ----------------
// gate(e) = sigmoid( sum_ch relu(u[src][ch] + v[dst][ch] + bg1[ch]) * Wg2[ch] + bg2 )
// h_out[n] = sum_e w*h[src] / (sum_e w + eps),  w = c*gate

__global__ __launch_bounds__(256) void k_gate_agg(
    const unsigned short* __restrict__ UV, const float* __restrict__ hf,
    const int* __restrict__ row_ptr, const int* __restrict__ src_perm,
    const float* __restrict__ c_perm,
    const float* __restrict__ bg1, const float* __restrict__ Wg2,
    const float* __restrict__ bg2p, float* __restrict__ out_f32)
{
  const int gw = (blockIdx.x*256 + threadIdx.x) >> 6;
  const int lane = threadIdx.x & 63;
  if(gw >= NN) return;

  // per-lane channels 2*lane, 2*lane+1
  const ushort2 vraw = *(const ushort2*)&UV[(size_t)gw*256 + 128 + lane*2];
  const float v0 = bf16_to_f32(vraw.x) + bg1[lane*2];
  const float v1 = bf16_to_f32(vraw.y) + bg1[lane*2 + 1];
  const float w20 = Wg2[lane*2], w21 = Wg2[lane*2 + 1];
  const float bg2v = bg2p[0];

  const int beg = row_ptr[gw], end = row_ptr[gw+1];
  float a0 = 0.f, a1 = 0.f, wsum = 0.f;

  for(int base = beg; base < end; base += 64){
    const int nb = min(64, end - base);
    const int  sv = (base + lane < end) ? src_perm[base + lane] : 0;
    const float cv = (base + lane < end) ? c_perm[base + lane] : 0.f;
    for(int j = 0; j < nb; j++){
      const int   s  = __shfl(sv, j);
      const float ce = __shfl(cv, j);
      const ushort2 ur = *(const ushort2*)&UV[(size_t)s*256 + lane*2];
      const f32x2  hv  = *(const f32x2*)&hf[(size_t)s*128 + lane*2];
      float tpart = fmaxf(v0 + bf16_to_f32(ur.x), 0.f)*w20
                  + fmaxf(v1 + bf16_to_f32(ur.y), 0.f)*w21;
      #pragma unroll
      for(int off = 32; off > 0; off >>= 1) tpart += __shfl_xor(tpart, off);
      const float g = 1.f/(1.f + __expf(-(tpart + bg2v)));
      const float w = ce * g;
      a0 += w*hv[0]; a1 += w*hv[1]; wsum += w;
    }
  }
  const float inv = 1.f/(wsum + EPSV);
  const size_t o = (size_t)gw*128 + lane*2;
  *(f32x2*)&out_f32[o] = (f32x2){a0*inv, a1*inv};
}

// ---------------- launch ----------------

extern "C" void kernel_launch(void* const* d_in, const int* in_sizes, int n_in,
                              void* d_out, int out_size, void* d_ws, size_t ws_size,
                              hipStream_t stream) {
  (void)in_sizes; (void)n_in; (void)out_size; (void)ws_size;
  const float* X      = (const float*)d_in[0];
  const int*   src    = (const int*)d_in[1];
  const int*   dst    = (const int*)d_in[2];
  const float* base_w = (const float*)d_in[3];
  const float* W1     = (const float*)d_in[4];
  const float* b1     = (const float*)d_in[5];
  const float* W2     = (const float*)d_in[6];
  const float* b2     = (const float*)d_in[7];
  const float* Wg1    = (const float*)d_in[8];
  const float* bg1    = (const float*)d_in[9];
  const float* Wg2    = (const float*)d_in[10];
  const float* bg2    = (const float*)d_in[11];
  const float* rho    = (const float*)d_in[12];

  char* ws = (char*)d_ws;
  size_t off = 0;
  auto alloc = [&](size_t bytes)->char*{ char* p = ws + off; off += (bytes + 255) & ~(size_t)255; return p; };
  unsigned short* W1T      = (unsigned short*)alloc((size_t)1024*128*2);
  unsigned short* W2T      = (unsigned short*)alloc((size_t)128*128*2);
  unsigned short* Wg1T     = (unsigned short*)alloc((size_t)256*128*2);
  int*            src_perm = (int*)alloc((size_t)EE*4);
  float*          c_perm   = (float*)alloc((size_t)EE*4);
  int*            row_ptr  = (int*)alloc((size_t)(NN+1)*4);
  int*            cursor   = (int*)alloc((size_t)NN*4);
  int*            counts   = (int*)alloc((size_t)NN*4);
  unsigned short* UV       = (unsigned short*)alloc((size_t)NN*256*2);
  float*          hf_B     = (float*)alloc((size_t)NN*128*4);
  float*          h0       = (float*)d_out;   // encoder f32 output lives in d_out

  hipMemsetAsync(counts, 0, (size_t)NN*4, stream);
  k_prep_w1t<<<512, 256, 0, stream>>>(W1, W1T);
  k_prep_w2t<<<64, 256, 0, stream>>>(W2, W2T);
  k_prep_wg1T<<<128, 256, 0, stream>>>(Wg1, Wg1T);
  k_hist<<<EE/256, 256, 0, stream>>>(dst, counts);
  k_scan<<<1, 1024, 0, stream>>>(counts, row_ptr, cursor);
  k_fill<<<EE/256, 256, 0, stream>>>(src, dst, base_w, rho, cursor, src_perm, c_perm);

  k_encoder<<<782, 256, 0, stream>>>(X, W1T, b1, W2T, b2, h0);

  // layer 1
  k_uv<<<782, 256, 0, stream>>>(h0, Wg1T, UV);
  k_gate_agg<<<12500, 256, 0, stream>>>(UV, h0, row_ptr, src_perm, c_perm, bg1, Wg2, bg2, hf_B);
  // layer 2
  k_uv<<<782, 256, 0, stream>>>(hf_B, Wg1T, UV);
  k_gate_agg<<<12500, 256, 0, stream>>>(UV, hf_B, row_ptr, src_perm, c_perm, bg1, Wg2, bg2, (float*)d_out);
}

// Round 3
// 658.686 us; speedup vs baseline: 1.9574x; 1.2378x over previous
//
#include <hip/hip_runtime.h>
#include <stdint.h>

#define NN 50000
#define CC 1024
#define HH 128
#define EE 1600000
#define EPSV 1e-8f
#define SCAN_BLKS 196   // ceil(50000/256)

typedef __attribute__((ext_vector_type(8))) short bf16x8;
typedef __attribute__((ext_vector_type(4))) float f32x4;
typedef __attribute__((ext_vector_type(2))) float f32x2;

__device__ __forceinline__ unsigned short f32_to_bf16(float f){
  union { float f; uint32_t u; } cv; cv.f = f;
  uint32_t u = cv.u;
  return (unsigned short)((u + 0x7FFFu + ((u >> 16) & 1u)) >> 16);
}
__device__ __forceinline__ float bf16lo_to_f32(uint32_t w){
  union { uint32_t u; float f; } cv; cv.u = w << 16; return cv.f;
}
__device__ __forceinline__ float bf16hi_to_f32(uint32_t w){
  union { uint32_t u; float f; } cv; cv.u = w & 0xFFFF0000u; return cv.f;
}

// ---------------- prep kernels ----------------

__global__ __launch_bounds__(256) void k_prep_w1t(const float* __restrict__ W1,
                                                  unsigned short* __restrict__ W1T){
  int idx = blockIdx.x*256 + threadIdx.x;          // 128*1024, W1T[n][k]
  if(idx >= 128*1024) return;
  int n = idx >> 10, k = idx & 1023;
  W1T[idx] = f32_to_bf16(W1[k*128 + n]);
}

__global__ __launch_bounds__(256) void k_prep_w2t(const float* __restrict__ W2,
                                                  unsigned short* __restrict__ W2T){
  int idx = blockIdx.x*256 + threadIdx.x;          // 128*128, W2T[n][k]
  if(idx >= 128*128) return;
  int n = idx >> 7, k = idx & 127;
  W2T[idx] = f32_to_bf16(W2[k*128 + n]);
}

// Wg1T[c][k], c in [0,256): c<128 -> u-col uses Wg1[k][c]; c>=128 -> v-col uses Wg1[128+k][c-128]
__global__ __launch_bounds__(256) void k_prep_wg1T(const float* __restrict__ Wg1,
                                                   unsigned short* __restrict__ T){
  int idx = blockIdx.x*256 + threadIdx.x;          // 256*128
  if(idx >= 256*128) return;
  int c = idx >> 7, k = idx & 127;
  int row = (c < 128) ? k : (128 + k);
  int col = (c < 128) ? c : (c - 128);
  T[idx] = f32_to_bf16(Wg1[row*128 + col]);
}

// ---------------- CSR build: hist + 3-kernel parallel scan + fill ----------------

__global__ __launch_bounds__(256) void k_hist(const int* __restrict__ dst,
                                              int* __restrict__ counts){
  int e = blockIdx.x*256 + threadIdx.x;
  if(e < EE) atomicAdd(&counts[dst[e]], 1);
}

__global__ __launch_bounds__(256) void k_scan1(const int* __restrict__ counts,
    int* __restrict__ lexcl, int* __restrict__ bsum){
  __shared__ int buf[256];
  const int t = threadIdx.x, i = blockIdx.x*256 + t;
  int v = (i < NN) ? counts[i] : 0;
  buf[t] = v;
  __syncthreads();
  for(int off = 1; off < 256; off <<= 1){
    int add = (t >= off) ? buf[t-off] : 0;
    __syncthreads();
    buf[t] += add;
    __syncthreads();
  }
  if(i < NN) lexcl[i] = buf[t] - v;
  if(t == 255) bsum[blockIdx.x] = buf[255];
}

__global__ __launch_bounds__(256) void k_scan2(const int* __restrict__ bsum,
    int* __restrict__ bexcl, int* __restrict__ row_ptr){
  __shared__ int buf[256];
  const int t = threadIdx.x;
  int v = (t < SCAN_BLKS) ? bsum[t] : 0;
  buf[t] = v;
  __syncthreads();
  for(int off = 1; off < 256; off <<= 1){
    int add = (t >= off) ? buf[t-off] : 0;
    __syncthreads();
    buf[t] += add;
    __syncthreads();
  }
  if(t < SCAN_BLKS) bexcl[t] = buf[t] - v;
  if(t == 255) row_ptr[NN] = buf[255];
}

__global__ __launch_bounds__(256) void k_scan3(const int* __restrict__ lexcl,
    const int* __restrict__ bexcl, int* __restrict__ row_ptr, int* __restrict__ cursor){
  const int i = blockIdx.x*256 + threadIdx.x;
  if(i >= NN) return;
  int e = lexcl[i] + bexcl[blockIdx.x];
  row_ptr[i] = e;
  cursor[i]  = e;
}

// fill CSR slots; computes c = base_w*sig(rho_src)*sig(rho_dst) inline into permuted order
__global__ __launch_bounds__(256) void k_fill(const int* __restrict__ src,
    const int* __restrict__ dst, const float* __restrict__ base_w,
    const float* __restrict__ rho_raw, int* __restrict__ cursor,
    int* __restrict__ src_perm, float* __restrict__ c_perm){
  int e = blockIdx.x*256 + threadIdx.x;
  if(e >= EE) return;
  int s = src[e], d = dst[e];
  int p = atomicAdd(&cursor[d], 1);
  float rs = 1.f/(1.f + __expf(-rho_raw[s]));
  float rd = 1.f/(1.f + __expf(-rho_raw[d]));
  src_perm[p] = s;
  c_perm[p]   = base_w[e]*rs*rd;
}

// ---------------- encoder: h = relu(relu(X@W1+b1)@W2+b2) -> f32 ----------------

__global__ __launch_bounds__(256) void k_encoder(
    const float* __restrict__ X, const unsigned short* __restrict__ W1T,
    const float* __restrict__ b1, const unsigned short* __restrict__ W2T,
    const float* __restrict__ b2, float* __restrict__ h_f32)
{
  __shared__ __attribute__((aligned(16))) unsigned short xA[64][40];
  __shared__ __attribute__((aligned(16))) unsigned short wB[128][40];
  __shared__ __attribute__((aligned(16))) unsigned short h1s[64][136];
  __shared__ __attribute__((aligned(16))) unsigned short w2s[128][136];

  const int t = threadIdx.x;
  const int wave = t >> 6, lane = t & 63;
  const int rowL = lane & 15, kq = lane >> 4;
  const int row0 = blockIdx.x * 64;

  for(int i = t; i < 2048; i += 256){
    int n = i >> 4, k8 = (i & 15) * 8;
    *(bf16x8*)&w2s[n][k8] = *(const bf16x8*)&W2T[n*128 + k8];
  }

  f32x4 acc[8] = {};
  for(int k0 = 0; k0 < 1024; k0 += 32){
    {
      int r = t >> 2, cbase = (t & 3) * 8;
      int gr = row0 + r; if(gr >= NN) gr = NN-1;
      const float* px = X + (size_t)gr*1024 + k0 + cbase;
      f32x4 v0 = *(const f32x4*)px;
      f32x4 v1 = *(const f32x4*)(px + 4);
      union { bf16x8 v; unsigned short s[8]; } pk;
      #pragma unroll
      for(int j = 0; j < 4; j++){ pk.s[j] = f32_to_bf16(v0[j]); pk.s[4+j] = f32_to_bf16(v1[j]); }
      *(bf16x8*)&xA[r][cbase] = pk.v;
    }
    {
      int n = t >> 1, cb = (t & 1) * 16;
      const unsigned short* p = W1T + n*1024 + k0 + cb;
      *(bf16x8*)&wB[n][cb]     = *(const bf16x8*)p;
      *(bf16x8*)&wB[n][cb + 8] = *(const bf16x8*)(p + 8);
    }
    __syncthreads();
    bf16x8 a = *(const bf16x8*)&xA[wave*16 + rowL][kq*8];
    #pragma unroll
    for(int nt = 0; nt < 8; nt++){
      bf16x8 b = *(const bf16x8*)&wB[nt*16 + rowL][kq*8];
      acc[nt] = __builtin_amdgcn_mfma_f32_16x16x32_bf16(a, b, acc[nt], 0, 0, 0);
    }
    __syncthreads();
  }

  #pragma unroll
  for(int nt = 0; nt < 8; nt++){
    #pragma unroll
    for(int r = 0; r < 4; r++){
      int rr_ = wave*16 + kq*4 + r;
      int cc  = nt*16 + rowL;
      h1s[rr_][cc] = f32_to_bf16(fmaxf(acc[nt][r] + b1[cc], 0.f));
    }
  }
  __syncthreads();

  f32x4 acc2[8] = {};
  #pragma unroll
  for(int ks = 0; ks < 4; ks++){
    bf16x8 a = *(const bf16x8*)&h1s[wave*16 + rowL][ks*32 + kq*8];
    #pragma unroll
    for(int nt = 0; nt < 8; nt++){
      bf16x8 b = *(const bf16x8*)&w2s[nt*16 + rowL][ks*32 + kq*8];
      acc2[nt] = __builtin_amdgcn_mfma_f32_16x16x32_bf16(a, b, acc2[nt], 0, 0, 0);
    }
  }
  #pragma unroll
  for(int nt = 0; nt < 8; nt++){
    #pragma unroll
    for(int r = 0; r < 4; r++){
      int gr = row0 + wave*16 + kq*4 + r;
      if(gr < NN){
        int cc = nt*16 + rowL;
        h_f32[(size_t)gr*128 + cc] = fmaxf(acc2[nt][r] + b2[cc], 0.f);
      }
    }
  }
}

// ---------------- node-table prep: UH[n] = [u bf16 | h bf16], Vf[n] = v + bg1 (f32) ----------------
// u = h@Wg1_top, v = h@Wg1_bot. block 256 (4 waves), tile 64 rows x 256 cols.

__global__ __launch_bounds__(256) void k_uv(
    const float* __restrict__ hf, const unsigned short* __restrict__ Wg1T,
    const float* __restrict__ bg1,
    unsigned short* __restrict__ UH, float* __restrict__ Vf)
{
  __shared__ __attribute__((aligned(16))) unsigned short As[64][136];
  const int t = threadIdx.x, wave = t >> 6, lane = t & 63;
  const int rowL = lane & 15, kq = lane >> 4;
  const int row0 = blockIdx.x * 64;

  {
    int r = t >> 2, cb = (t & 3) * 32;
    int gr = row0 + r;
    bool valid = (gr < NN);
    if(!valid) gr = NN-1;
    const float* p = hf + (size_t)gr*128 + cb;
    #pragma unroll
    for(int j8 = 0; j8 < 4; j8++){
      f32x4 v0 = *(const f32x4*)(p + j8*8);
      f32x4 v1 = *(const f32x4*)(p + j8*8 + 4);
      union { bf16x8 v; unsigned short s[8]; } pk;
      #pragma unroll
      for(int j = 0; j < 4; j++){ pk.s[j] = f32_to_bf16(v0[j]); pk.s[4+j] = f32_to_bf16(v1[j]); }
      *(bf16x8*)&As[r][cb + j8*8] = pk.v;
      if(valid) *(bf16x8*)&UH[(size_t)(row0+r)*256 + 128 + cb + j8*8] = pk.v;  // h-half
    }
  }
  __syncthreads();

  f32x4 acc[16] = {};
  #pragma unroll
  for(int ks = 0; ks < 4; ks++){
    bf16x8 a = *(const bf16x8*)&As[wave*16 + rowL][ks*32 + kq*8];
    #pragma unroll
    for(int nt = 0; nt < 16; nt++){
      bf16x8 b = *(const bf16x8*)&Wg1T[(size_t)(nt*16 + rowL)*128 + ks*32 + kq*8];
      acc[nt] = __builtin_amdgcn_mfma_f32_16x16x32_bf16(a, b, acc[nt], 0, 0, 0);
    }
  }
  #pragma unroll
  for(int nt = 0; nt < 16; nt++){
    #pragma unroll
    for(int r = 0; r < 4; r++){
      int gr = row0 + wave*16 + kq*4 + r;
      if(gr < NN){
        int col = nt*16 + rowL;
        if(col < 128) UH[(size_t)gr*256 + col] = f32_to_bf16(acc[nt][r]);     // u-half
        else          Vf[(size_t)gr*128 + col - 128] = acc[nt][r] + bg1[col - 128];
      }
    }
  }
}

// ---------------- fused gate + aggregation, CSR order, one wave per dst node ----------------
// gate phase: 4 edges per iteration, 16 lanes/edge, 8 channels/lane (v+bg1, Wg2 in regs).
// agg phase: lane = 2 channels, h gathered as bf16x2 from UH's h-half.

__global__ __launch_bounds__(256) void k_gate_agg(
    const unsigned short* __restrict__ UH, const float* __restrict__ Vf,
    const int* __restrict__ row_ptr, const int* __restrict__ src_perm,
    const float* __restrict__ c_perm,
    const float* __restrict__ Wg2, const float* __restrict__ bg2p,
    float* __restrict__ out_f32)
{
  __shared__ float2 ws_s[4][64];
  const int wv = threadIdx.x >> 6, lane = threadIdx.x & 63;
  const int gw = blockIdx.x*4 + wv;
  if(gw >= NN) return;
  const int eq = lane >> 4, li = lane & 15;

  // loop-invariant per-lane gate coefficients (8 channels each)
  f32x4 va = *(const f32x4*)(Vf + (size_t)gw*128 + li*8);
  f32x4 vb = *(const f32x4*)(Vf + (size_t)gw*128 + li*8 + 4);
  f32x4 wa = *(const f32x4*)(Wg2 + li*8);
  f32x4 wb = *(const f32x4*)(Wg2 + li*8 + 4);
  const float vch[8]  = {va[0],va[1],va[2],va[3],vb[0],vb[1],vb[2],vb[3]};
  const float w2ch[8] = {wa[0],wa[1],wa[2],wa[3],wb[0],wb[1],wb[2],wb[3]};
  const float bg2v = bg2p[0];

  const int beg = row_ptr[gw], end = row_ptr[gw+1];
  float a0 = 0.f, a1 = 0.f, wsum = 0.f;

  for(int base = beg; base < end; base += 64){
    const int nb = min(64, end - base);
    // ---- gate: 4 edges per iteration ----
    for(int q = 0; q < nb; q += 4){
      const int  idx  = q + eq;
      const bool ok   = (idx < nb);
      const int  slot = base + (ok ? idx : 0);
      const int  s    = src_perm[slot];
      const float cv  = c_perm[slot];
      union { bf16x8 v; uint32_t u32[4]; } uu;
      uu.v = *(const bf16x8*)&UH[(size_t)s*256 + li*8];
      float tacc = 0.f;
      #pragma unroll
      for(int p = 0; p < 4; p++){
        const uint32_t w2b = uu.u32[p];
        tacc += fmaxf(bf16lo_to_f32(w2b) + vch[2*p],   0.f) * w2ch[2*p];
        tacc += fmaxf(bf16hi_to_f32(w2b) + vch[2*p+1], 0.f) * w2ch[2*p+1];
      }
      // reduce over the 16-lane group (xor 1,2,4,8) via ds_swizzle
      tacc += __int_as_float(__builtin_amdgcn_ds_swizzle(__float_as_int(tacc), 0x041F));
      tacc += __int_as_float(__builtin_amdgcn_ds_swizzle(__float_as_int(tacc), 0x081F));
      tacc += __int_as_float(__builtin_amdgcn_ds_swizzle(__float_as_int(tacc), 0x101F));
      tacc += __int_as_float(__builtin_amdgcn_ds_swizzle(__float_as_int(tacc), 0x201F));
      const float g = 1.f/(1.f + __expf(-(tacc + bg2v)));
      if(li == 0 && ok) ws_s[wv][idx] = make_float2(cv*g, __int_as_float(s));
    }
    // ---- aggregate ----
    #pragma unroll 4
    for(int j = 0; j < nb; j++){
      const float2 p = ws_s[wv][j];
      const float w  = p.x;
      const int   s  = __float_as_int(p.y);
      const uint32_t hw = *(const uint32_t*)&UH[(size_t)s*256 + 128 + lane*2];
      a0 += w*bf16lo_to_f32(hw);
      a1 += w*bf16hi_to_f32(hw);
      wsum += w;
    }
  }
  const float inv = 1.f/(wsum + EPSV);
  const size_t o = (size_t)gw*128 + lane*2;
  *(f32x2*)&out_f32[o] = (f32x2){a0*inv, a1*inv};
}

// ---------------- launch ----------------

extern "C" void kernel_launch(void* const* d_in, const int* in_sizes, int n_in,
                              void* d_out, int out_size, void* d_ws, size_t ws_size,
                              hipStream_t stream) {
  (void)in_sizes; (void)n_in; (void)out_size; (void)ws_size;
  const float* X      = (const float*)d_in[0];
  const int*   src    = (const int*)d_in[1];
  const int*   dst    = (const int*)d_in[2];
  const float* base_w = (const float*)d_in[3];
  const float* W1     = (const float*)d_in[4];
  const float* b1     = (const float*)d_in[5];
  const float* W2     = (const float*)d_in[6];
  const float* b2     = (const float*)d_in[7];
  const float* Wg1    = (const float*)d_in[8];
  const float* bg1    = (const float*)d_in[9];
  const float* Wg2    = (const float*)d_in[10];
  const float* bg2    = (const float*)d_in[11];
  const float* rho    = (const float*)d_in[12];

  char* ws = (char*)d_ws;
  size_t off = 0;
  auto alloc = [&](size_t bytes)->char*{ char* p = ws + off; off += (bytes + 255) & ~(size_t)255; return p; };
  unsigned short* W1T      = (unsigned short*)alloc((size_t)1024*128*2);
  unsigned short* W2T      = (unsigned short*)alloc((size_t)128*128*2);
  unsigned short* Wg1T     = (unsigned short*)alloc((size_t)256*128*2);
  int*            src_perm = (int*)alloc((size_t)EE*4);
  float*          c_perm   = (float*)alloc((size_t)EE*4);
  int*            row_ptr  = (int*)alloc((size_t)(NN+1)*4);
  int*            cursor   = (int*)alloc((size_t)NN*4);
  int*            counts   = (int*)alloc((size_t)NN*4);
  int*            lexcl    = (int*)alloc((size_t)NN*4);
  int*            bsum     = (int*)alloc((size_t)256*4);
  int*            bexcl    = (int*)alloc((size_t)256*4);
  unsigned short* UH       = (unsigned short*)alloc((size_t)NN*256*2);
  float*          Vf       = (float*)alloc((size_t)NN*128*4);
  float*          hf_B     = (float*)alloc((size_t)NN*128*4);
  float*          h0       = (float*)d_out;   // encoder f32 output lives in d_out

  hipMemsetAsync(counts, 0, (size_t)NN*4, stream);
  k_prep_w1t<<<512, 256, 0, stream>>>(W1, W1T);
  k_prep_w2t<<<64, 256, 0, stream>>>(W2, W2T);
  k_prep_wg1T<<<128, 256, 0, stream>>>(Wg1, Wg1T);
  k_hist<<<EE/256, 256, 0, stream>>>(dst, counts);
  k_scan1<<<SCAN_BLKS, 256, 0, stream>>>(counts, lexcl, bsum);
  k_scan2<<<1, 256, 0, stream>>>(bsum, bexcl, row_ptr);
  k_scan3<<<SCAN_BLKS, 256, 0, stream>>>(lexcl, bexcl, row_ptr, cursor);
  k_fill<<<EE/256, 256, 0, stream>>>(src, dst, base_w, rho, cursor, src_perm, c_perm);

  k_encoder<<<782, 256, 0, stream>>>(X, W1T, b1, W2T, b2, h0);

  // layer 1
  k_uv<<<782, 256, 0, stream>>>(h0, Wg1T, bg1, UH, Vf);
  k_gate_agg<<<12500, 256, 0, stream>>>(UH, Vf, row_ptr, src_perm, c_perm, Wg2, bg2, hf_B);
  // layer 2
  k_uv<<<782, 256, 0, stream>>>(hf_B, Wg1T, bg1, UH, Vf);
  k_gate_agg<<<12500, 256, 0, stream>>>(UH, Vf, row_ptr, src_perm, c_perm, Wg2, bg2, (float*)d_out);
}